// Round 4
// baseline (1481.950 us; speedup 1.0000x reference)
//
#include <hip/hip_runtime.h>
#include <math.h>

typedef unsigned int u32;
typedef unsigned long long u64;

#define HWSZ 16384
#define NCAND 1000
#define CAP 1024
#define NDET 100

__device__ __forceinline__ float sigmoidf_(float x) {
  return 1.0f / (1.0f + expf(-x));
}

// Per-wave phase stagger (validated in the round-0 580us kernel; kept).
__device__ __forceinline__ void wave_stagger(int wid) {
  switch (wid) {
    case 1: __builtin_amdgcn_s_sleep(1); break;
    case 2: __builtin_amdgcn_s_sleep(2); break;
    case 3: __builtin_amdgcn_s_sleep(3); break;
    case 4: __builtin_amdgcn_s_sleep(4); break;
    case 5: __builtin_amdgcn_s_sleep(5); break;
    case 6: __builtin_amdgcn_s_sleep(6); break;
    case 7: __builtin_amdgcn_s_sleep(7); break;
    case 8: __builtin_amdgcn_s_sleep(8); break;
    case 9: __builtin_amdgcn_s_sleep(9); break;
    case 10: __builtin_amdgcn_s_sleep(10); break;
    case 11: __builtin_amdgcn_s_sleep(11); break;
    case 12: __builtin_amdgcn_s_sleep(12); break;
    case 13: __builtin_amdgcn_s_sleep(13); break;
    case 14: __builtin_amdgcn_s_sleep(14); break;
    case 15: __builtin_amdgcn_s_sleep(15); break;
    default: break;
  }
}

// ---------------------------------------------------------------------------
// Fused obj+cls heads — round-13.
//
// MEASURED HISTORY:
//  r0  scalar-W: 580us, VALUBusy 55%, VGPR 52. Model (validated): per SIMD
//      per stage 4 waves x 16KB W = 1024 scalar line misses x ~60cy
//      SERIALIZED ~= 61k idle cy vs 65k FMA cy -> 52% busy. Scalar-unit miss
//      serialization is the wall.
//  r1/r3 vector-W: VGPR_Count = EXACTLY 64 + 12.5MB scratch both times.
//      Diagnosis: __launch_bounds__(1024,4) is unsatisfiable (16-wave block,
//      "4/CU") -> dropped -> allocator targets 8 waves/EU = 64-VGPR budget
//      and spills to protect occupancy that is LDS-capped at 4 waves/EU
//      anyway (136KB LDS = 1 block/CU).
//  r2  LDS-W windows: barrier lockstep + same 64-reg spill trap. 55% busy.
//
// ROUND-13 = round-0 source + exactly two changes:
//  (1) amdgpu_waves_per_eu(4,4): tells the allocator the truth (occupancy is
//      LDS-capped at 4 waves/EU) -> 128-VGPR budget, no spill.
//  (2) W loads on the VMEM path: wave-uniform address = SGPR quad-base +
//      ONE opaque-zero VGPR voffset + imm(<=3072). 4-row load/FMA interleave
//      caps W liveness. VMEM misses are handled in parallel (TCP/L2 MSHRs),
//      waits are counted in-order vmcnt -> hidden by 4 waves round-robin.
// Arithmetic BIT-IDENTICAL to r0: per acc[r], k = 0..255 ascending, same
// contraction order and operand values. absmax must stay 0.0.
// Tripwire: VGPR=64 + WRITE_SIZE>>1MB again => source-level cap immovable,
// abandon W-path family.
// ---------------------------------------------------------------------------
template <int NROWS, bool FULLROWS>
__device__ __forceinline__ void run_gemm(const float* __restrict__ Wm,
                                         const float (*X)[128], int rbase,
                                         int p0, float2 acc[16]) {
#pragma unroll
  for (int r = 0; r < 16; ++r) {
    acc[r].x = 0.f;
    acc[r].y = 0.f;
  }
  wave_stagger(rbase >> 4);
  if (rbase < NROWS) {
    int vzero = 0;
    asm volatile("" : "+v"(vzero));  // opaque zero pinned in a VGPR
    const char* W0 = (const char*)(Wm + (size_t)rbase * 256);
    const char* W1 = W0 + 4096;
    const char* W2 = W0 + 8192;
    const char* W3 = W0 + 12288;
#pragma unroll 1
    for (int kb = 0; kb < 64; ++kb) {
      const unsigned vo = (unsigned)(kb * 16) + (unsigned)vzero;
      const float2 xv0 = *(const float2*)&X[kb * 4 + 0][p0];
      const float2 xv1 = *(const float2*)&X[kb * 4 + 1][p0];
      const float2 xv2 = *(const float2*)&X[kb * 4 + 2][p0];
      const float2 xv3 = *(const float2*)&X[kb * 4 + 3][p0];
#pragma unroll
      for (int g = 0; g < 4; ++g) {
        const char* Wg = (g == 0) ? W0 : (g == 1) ? W1 : (g == 2) ? W2 : W3;
        float4 w0 = {0.f, 0.f, 0.f, 0.f};
        float4 w1 = {0.f, 0.f, 0.f, 0.f};
        float4 w2 = {0.f, 0.f, 0.f, 0.f};
        float4 w3 = {0.f, 0.f, 0.f, 0.f};
        if (FULLROWS || rbase + 4 * g + 0 < NROWS)
          w0 = *(const float4*)(Wg + vo);
        if (FULLROWS || rbase + 4 * g + 1 < NROWS)
          w1 = *(const float4*)(Wg + vo + 1024);
        if (FULLROWS || rbase + 4 * g + 2 < NROWS)
          w2 = *(const float4*)(Wg + vo + 2048);
        if (FULLROWS || rbase + 4 * g + 3 < NROWS)
          w3 = *(const float4*)(Wg + vo + 3072);
#pragma unroll
        for (int rr = 0; rr < 4; ++rr) {
          const int r = 4 * g + rr;
          if (FULLROWS || rbase + r < NROWS) {
            const float4 wv = (rr == 0) ? w0 : (rr == 1) ? w1
                                         : (rr == 2) ? w2 : w3;
            acc[r].x += wv.x * xv0.x;
            acc[r].y += wv.x * xv0.y;
            acc[r].x += wv.y * xv1.x;
            acc[r].y += wv.y * xv1.y;
            acc[r].x += wv.z * xv2.x;
            acc[r].y += wv.z * xv2.y;
            acc[r].x += wv.w * xv3.x;
            acc[r].y += wv.w * xv3.y;
          }
        }
      }
    }
  }
}

__global__ __attribute__((amdgpu_waves_per_eu(4, 4)))
__launch_bounds__(1024) void heads_fused(
    const float* __restrict__ feat, const float* __restrict__ ow_in,
    const float* __restrict__ ob_in, const float* __restrict__ ow_hid,
    const float* __restrict__ ob_hid, const float* __restrict__ ow_out,
    const float* __restrict__ ob_out, const float* __restrict__ cw_in,
    const float* __restrict__ cb_in, const float* __restrict__ cw_hid,
    const float* __restrict__ cb_hid, const float* __restrict__ cw_out,
    const float* __restrict__ cb_out, float* __restrict__ score,
    int* __restrict__ label) {
  __shared__ __align__(16) float X[256][128];  // 128 KB
  __shared__ float objL[128];
  __shared__ float smax[5][128];
  __shared__ int sarg[5][128];

  const int tid = threadIdx.x;
  const int wid = __builtin_amdgcn_readfirstlane(tid >> 6);
  const int ln = tid & 63;
  const int p0 = 2 * ln;
  const int rbase = wid * 16;
  const int batch = blockIdx.x >> 7;
  const int pbase = (blockIdx.x & 127) * 128;
  const float* fb = feat + (size_t)batch * 256 * HWSZ;

  for (int head = 0; head < 2; ++head) {
    const float* w_in = head ? cw_in : ow_in;
    const float* b_in = head ? cb_in : ob_in;
    const float* w_hid = head ? cw_hid : ow_hid;
    const float* b_hid = head ? cb_hid : ob_hid;

    // ---- stage feat -> X ----
#pragma unroll
    for (int m = 0; m < 8; ++m) {
      int f4 = tid + 1024 * m;
      int c = f4 >> 5, col4 = (f4 & 31) * 4;
      *(float4*)&X[c][col4] =
          *(const float4*)(fb + (size_t)c * HWSZ + pbase + col4);
    }
    __syncthreads();

    float2 acc[16];
    // ---- 5 GEMM stages (in-conv + 4 residual hidden) ----
    for (int s = 0; s < 5; ++s) {
      const float* Wm = (s == 0) ? w_in : (w_hid + (size_t)(s - 1) * 65536);
      const float* bs = (s == 0) ? b_in : (b_hid + (s - 1) * 256);
      run_gemm<256, true>(Wm, X, rbase, p0, acc);
      __syncthreads();  // all reads of X complete
#pragma unroll
      for (int r = 0; r < 16; ++r) {
        float b = bs[rbase + r];
        float2 v = make_float2(acc[r].x + b, acc[r].y + b);
        if (s > 0) {  // residual: h + (conv + b)
          v.x += X[rbase + r][p0];
          v.y += X[rbase + r][p0 + 1];
        }
        *(float2*)&X[rbase + r][p0] = v;
      }
      __syncthreads();
    }

    if (head == 0) {
      // ---- obj out: row 0 only ----
      run_gemm<2, false>(ow_out, X, rbase, p0, acc);
      if (wid == 0) {
        float bo = ob_out[0];
        objL[p0] = sigmoidf_(acc[0].x + bo);
        objL[p0 + 1] = sigmoidf_(acc[0].y + bo);
      }
      __syncthreads();  // objL visible; X reads drained before restage
    } else {
      // ---- cls out: 80 class rows over waves 0..4 ----
      run_gemm<80, true>(cw_out, X, rbase, p0, acc);
      if (rbase < 80) {
        float ob0 = objL[p0], ob1 = objL[p0 + 1];
        float best0 = -1.f, best1 = -1.f;
        int a0 = 0, a1 = 0;
#pragma unroll
        for (int r = 0; r < 16; ++r) {
          float bb = cb_out[rbase + r];
          float s0 = sigmoidf_(acc[r].x + bb) * ob0;
          float s1 = sigmoidf_(acc[r].y + bb) * ob1;
          if (s0 > best0) {
            best0 = s0;
            a0 = rbase + r;
          }
          if (s1 > best1) {
            best1 = s1;
            a1 = rbase + r;
          }
        }
        smax[wid][p0] = best0;
        sarg[wid][p0] = a0;
        smax[wid][p0 + 1] = best1;
        sarg[wid][p0 + 1] = a1;
      }
      __syncthreads();
      if (tid < 128) {
        float best = -1.f;
        int ba = 0;
        for (int g = 0; g < 5; ++g) {  // ascending class blocks: first-max wins
          float m = smax[g][tid];
          if (m > best) {
            best = m;
            ba = sarg[g][tid];
          }
        }
        score[batch * HWSZ + pbase + tid] = best;
        label[batch * HWSZ + pbase + tid] = ba;
      }
    }
  }
}

// ---------------------------------------------------------------------------
// ENTIRE box head in one kernel: 256 blocks x 8 candidates (validated r3-r9).
// ---------------------------------------------------------------------------
__global__ __launch_bounds__(1024) void box_all(
    const float* __restrict__ feat, const int* __restrict__ cand_idx,
    const float* __restrict__ w_in, const float* __restrict__ b_in,
    const float* __restrict__ w_hid, const float* __restrict__ b_hid,
    const float* __restrict__ w_out, const float* __restrict__ b_out,
    float* __restrict__ cand_box) {
  __shared__ float h[256][8];  // 8 KB
  const int tid = threadIdx.x;
  const int batch = blockIdx.x >> 7;
  const int cbase = (blockIdx.x & 127) * 8;
  const float* fb = feat + (size_t)batch * 256 * HWSZ;

  for (int i = tid; i < 2048; i += 1024) {
    int k = i >> 3, c = i & 7;
    int r = cbase + c;
    float v = 0.f;
    if (r < NCAND) {
      int hw = cand_idx[batch * CAP + r];
      v = fb[(size_t)k * HWSZ + hw];
    }
    h[k][c] = v;
  }
  __syncthreads();

  const int wid = tid >> 6, ln = tid & 63;
  const int c = ln & 7, rr = ln >> 3;
  const int r0 = wid * 16 + rr, r1 = wid * 16 + 8 + rr;

  for (int s = 0; s < 5; ++s) {
    const float* Wm = (s == 0) ? w_in : (w_hid + (size_t)(s - 1) * 65536);
    const float* bs = (s == 0) ? b_in : (b_hid + (s - 1) * 256);
    float a0 = 0.f, a1 = 0.f;
    for (int kb = 0; kb < 64; ++kb) {
      float4 w0 = *(const float4*)&Wm[(size_t)r0 * 256 + kb * 4];
      float4 w1 = *(const float4*)&Wm[(size_t)r1 * 256 + kb * 4];
      float x0 = h[kb * 4 + 0][c], x1 = h[kb * 4 + 1][c];
      float x2 = h[kb * 4 + 2][c], x3 = h[kb * 4 + 3][c];
      a0 += w0.x * x0;
      a0 += w0.y * x1;
      a0 += w0.z * x2;
      a0 += w0.w * x3;
      a1 += w1.x * x0;
      a1 += w1.y * x1;
      a1 += w1.z * x2;
      a1 += w1.w * x3;
    }
    __syncthreads();
    float v0 = a0 + bs[r0], v1 = a1 + bs[r1];
    if (s > 0) {
      v0 += h[r0][c];
      v1 += h[r1][c];
    }
    h[r0][c] = v0;
    h[r1][c] = v1;
    __syncthreads();
  }

  if (tid < 32) {
    int row = tid >> 3, cc = tid & 7;
    int r = cbase + cc;
    if (r < NCAND) {
      float s = 0.f;
      for (int k = 0; k < 256; ++k) s += w_out[row * 256 + k] * h[k][cc];
      s += b_out[row];
      float e = expf(s) * 8.f;
      int hw = cand_idx[batch * CAP + r];
      int hh = hw >> 7, wwp = hw & 127;
      float px = (wwp + 0.5f) * 8.f, py = (hh + 0.5f) * 8.f;
      float coord = (row == 0)   ? px - e
                    : (row == 1) ? py - e
                    : (row == 2) ? px + e
                                 : py + e;
      cand_box[(size_t)(batch * CAP + r) * 4 + row] = coord;
    }
  }
}

// ---------------------------------------------------------------------------
// Exact top-1000 per batch (bitwise-validated rounds 1-9). Skip the
// 2048-wide tie bitonic when only one element equals the threshold (the
// overwhelmingly common case for continuous scores); general path kept.
// ---------------------------------------------------------------------------
__device__ __forceinline__ void suffix2048(u32* hist, int tid) {
  for (int d = 1; d < 2048; d <<= 1) {
    u32 v0 = hist[tid] + ((tid + d < 2048) ? hist[tid + d] : 0u);
    u32 v1 =
        hist[tid + 1024] + ((tid + 1024 + d < 2048) ? hist[tid + 1024 + d] : 0u);
    __syncthreads();
    hist[tid] = v0;
    hist[tid + 1024] = v1;
    __syncthreads();
  }
}

__global__ __launch_bounds__(1024) void topk_kernel(
    const float* __restrict__ score, const int* __restrict__ label,
    float* __restrict__ cand_sc, int* __restrict__ cand_idx,
    int* __restrict__ cand_lab) {
  __shared__ u32 hist[2048];
  __shared__ u64 buf[CAP];
  __shared__ u32 tiebuf[2048];
  __shared__ int sres[2];
  __shared__ int cA, cT;
  const int tid = threadIdx.x;
  const int b = blockIdx.x;
  const int base = b * HWSZ;
  u32 bits[16];
#pragma unroll
  for (int m = 0; m < 16; ++m)
    bits[m] = __float_as_uint(score[base + tid + 1024 * m]);

  int K = NCAND;
  u32 hi = 0;
  u32 thresh = 0;
  for (int lev = 0; lev < 3; ++lev) {
    hist[tid] = 0;
    hist[tid + 1024] = 0;
    __syncthreads();
#pragma unroll
    for (int m = 0; m < 16; ++m) {
      u32 v = bits[m];
      bool ok;
      int bin;
      if (lev == 0) {
        ok = true;
        bin = v >> 21;
      } else if (lev == 1) {
        ok = ((v >> 21) == hi);
        bin = (v >> 10) & 2047;
      } else {
        ok = ((v >> 10) == hi);
        bin = v & 1023;
      }
      if (ok) atomicAdd(&hist[bin], 1u);
    }
    __syncthreads();
    suffix2048(hist, tid);
#pragma unroll
    for (int e = 0; e < 2; ++e) {
      int i = tid + e * 1024;
      int Si = (int)hist[i];
      int Sn = (i + 1 < 2048) ? (int)hist[i + 1] : 0;
      if (Si >= K && Sn < K) {
        sres[0] = i;
        sres[1] = Sn;
      }
    }
    __syncthreads();
    int B = sres[0];
    K -= sres[1];
    if (lev == 0) hi = (u32)B;
    else if (lev == 1) hi = (hi << 11) | (u32)B;
    else thresh = (hi << 10) | (u32)B;
    __syncthreads();
  }
  const int T = K;

  if (tid == 0) {
    cA = 0;
    cT = 0;
  }
  __syncthreads();
#pragma unroll
  for (int m = 0; m < 16; ++m) {
    u32 v = bits[m];
    int idxp = tid + 1024 * m;
    if (v > thresh) {
      int pos = atomicAdd(&cA, 1);
      buf[pos] = ((u64)(~v) << 32) | (u32)idxp;
    } else if (v == thresh) {
      int pos = atomicAdd(&cT, 1);
      if (pos < 2048) tiebuf[pos] = (u32)idxp;
    }
  }
  __syncthreads();
  const int A = cA;
  int nT = cT < 2048 ? cT : 2048;
  for (int i = tid; i < 2048; i += 1024)
    if (i >= nT) tiebuf[i] = 0xFFFFFFFFu;
  __syncthreads();
  if (nT > 1) {  // sort ties ascending by pixel index (rare path)
    for (int k = 2; k <= 2048; k <<= 1)
      for (int j = k >> 1; j > 0; j >>= 1) {
#pragma unroll
        for (int e = 0; e < 2; ++e) {
          int i = tid + e * 1024;
          int l = i ^ j;
          if (l > i) {
            u32 a = tiebuf[i], bb = tiebuf[l];
            bool up = ((i & k) == 0);
            if ((a > bb) == up) {
              tiebuf[i] = bb;
              tiebuf[l] = a;
            }
          }
        }
        __syncthreads();
      }
  }
  for (int t2 = tid; t2 < T; t2 += 1024)
    buf[A + t2] = ((u64)(~thresh) << 32) | tiebuf[t2];
  for (int i = tid; i < CAP; i += 1024)
    if (i >= NCAND) buf[i] = 0xFFFFFFFFFFFFFFFFull;
  __syncthreads();
  for (int k = 2; k <= 1024; k <<= 1)
    for (int j = k >> 1; j > 0; j >>= 1) {
      int i = tid, l = i ^ j;
      if (l > i) {
        u64 a = buf[i], bb = buf[l];
        bool up = ((i & k) == 0);
        if ((a > bb) == up) {
          buf[i] = bb;
          buf[l] = a;
        }
      }
      __syncthreads();
    }
  if (tid < NCAND) {
    u64 kv = buf[tid];
    u32 sb = ~(u32)(kv >> 32);
    int pix = (int)(kv & 0xFFFFFFFFull);
    cand_sc[b * CAP + tid] = __uint_as_float(sb);
    cand_idx[b * CAP + tid] = pix;
    cand_lab[b * CAP + tid] = label[base + pix];
  }
}

// ---------------------------------------------------------------------------
// NMS mask + fused sequential-suppress/assemble (unchanged, validated).
// ---------------------------------------------------------------------------
__global__ __launch_bounds__(1024) void nms_mask(
    const float* __restrict__ cand_box, u64* __restrict__ mask) {
  int bid = blockIdx.x;
  int b = bid / NCAND, i = bid % NCAND;
  int j = threadIdx.x;
  const float* bi = cand_box + (size_t)(b * CAP + i) * 4;
  float ix1 = bi[0], iy1 = bi[1], ix2 = bi[2], iy2 = bi[3];
  bool pred = false;
  if (j < NCAND && j > i) {
    const float* bj = cand_box + (size_t)(b * CAP + j) * 4;
    float jx1 = bj[0], jy1 = bj[1], jx2 = bj[2], jy2 = bj[3];
    float ai = fmaxf(ix2 - ix1, 0.f) * fmaxf(iy2 - iy1, 0.f);
    float aj = fmaxf(jx2 - jx1, 0.f) * fmaxf(jy2 - jy1, 0.f);
    float lx = fmaxf(ix1, jx1), ly = fmaxf(iy1, jy1);
    float rx = fminf(ix2, jx2), ry = fminf(iy2, jy2);
    float w = fmaxf(rx - lx, 0.f), h = fmaxf(ry - ly, 0.f);
    float inter = w * h;
    float iou = inter / (ai + aj - inter + 1e-6f);
    pred = iou > 0.65f;
  }
  u64 word = __ballot(pred);
  if ((j & 63) == 0) mask[(size_t)b * 16384 + i * 16 + (j >> 6)] = word;
}

__global__ void nms_finish(const u64* __restrict__ mask,
                           const float* __restrict__ cand_sc,
                           const int* __restrict__ cand_lab,
                           const float* __restrict__ cand_box,
                           float* __restrict__ out) {
  __shared__ u64 M[16000];
  int b = blockIdx.x, lane = threadIdx.x;  // 64 threads
  for (int m = lane; m < 16000; m += 64) M[m] = mask[(size_t)b * 16384 + m];
  __syncthreads();
  u64 kw = 0ull;
  if (lane < 15) kw = ~0ull;
  else if (lane == 15) kw = (1ull << 40) - 1;
  for (int i = 0; i < NCAND; ++i) {
    u64 wi = __shfl(kw, i >> 6);
    if ((wi >> (i & 63)) & 1ull) {
      if (lane < 16) kw &= ~M[i * 16 + lane];
    }
  }
  u64 valid = 0ull;
  if (lane < 15) valid = ~0ull;
  else if (lane == 15) valid = (1ull << 40) - 1;
  kw &= valid;
  u64 sup = valid & ~kw;
  int ck = __popcll(kw), cs = __popcll(sup);
  int preK = 0, preS = 0, totK = 0;
  for (int q = 0; q < 16; ++q) {
    int vk = __shfl(ck, q), vs = __shfl(cs, q);
    if (q < lane) {
      preK += vk;
      preS += vs;
    }
    totK += vk;
  }
  float* obox = out;
  float* osc = out + 2 * NDET * 4;
  float* olab = out + 2 * NDET * 4 + 2 * NDET;
  if (lane < 16) {
    u64 m = kw;
    int pos = preK;
    while (m) {
      int bit = __ffsll((unsigned long long)m) - 1;
      m &= m - 1;
      int j = lane * 64 + bit;
      if (pos < NDET) {
        osc[b * NDET + pos] = cand_sc[b * CAP + j];
        olab[b * NDET + pos] = (float)cand_lab[b * CAP + j];
        const float* bx = cand_box + (size_t)(b * CAP + j) * 4;
        float* dst = obox + (size_t)(b * NDET + pos) * 4;
        dst[0] = bx[0];
        dst[1] = bx[1];
        dst[2] = bx[2];
        dst[3] = bx[3];
      }
      ++pos;
    }
    m = sup;
    pos = totK + preS;
    while (m) {
      int bit = __ffsll((unsigned long long)m) - 1;
      m &= m - 1;
      int j = lane * 64 + bit;
      if (pos < NDET) {
        osc[b * NDET + pos] = 0.0f;
        olab[b * NDET + pos] = (float)cand_lab[b * CAP + j];
        const float* bx = cand_box + (size_t)(b * CAP + j) * 4;
        float* dst = obox + (size_t)(b * NDET + pos) * 4;
        dst[0] = bx[0];
        dst[1] = bx[1];
        dst[2] = bx[2];
        dst[3] = bx[3];
      }
      ++pos;
    }
  }
}

extern "C" void kernel_launch(void* const* d_in, const int* in_sizes, int n_in,
                              void* d_out, int out_size, void* d_ws,
                              size_t ws_size, hipStream_t stream) {
  (void)in_sizes;
  (void)n_in;
  (void)out_size;
  (void)ws_size;
  const float* feat = (const float*)d_in[0];
  const float* cls_w_in = (const float*)d_in[1];
  const float* cls_b_in = (const float*)d_in[2];
  const float* cls_w_hid = (const float*)d_in[3];
  const float* cls_b_hid = (const float*)d_in[4];
  const float* cls_w_out = (const float*)d_in[5];
  const float* cls_b_out = (const float*)d_in[6];
  const float* obj_w_in = (const float*)d_in[7];
  const float* obj_b_in = (const float*)d_in[8];
  const float* obj_w_hid = (const float*)d_in[9];
  const float* obj_b_hid = (const float*)d_in[10];
  const float* obj_w_out = (const float*)d_in[11];
  const float* obj_b_out = (const float*)d_in[12];
  const float* box_w_in = (const float*)d_in[13];
  const float* box_b_in = (const float*)d_in[14];
  const float* box_w_hid = (const float*)d_in[15];
  const float* box_b_hid = (const float*)d_in[16];
  const float* box_w_out = (const float*)d_in[17];
  const float* box_b_out = (const float*)d_in[18];
  float* out = (float*)d_out;

  char* w = (char*)d_ws;
  float* scoreArr = (float*)w;             // 131072 B
  int* labelArr = (int*)(w + 131072);      // 131072 B
  float* cand_sc = (float*)(w + 262144);   // 8192 B
  int* cand_idx = (int*)(w + 270336);      // 8192 B
  int* cand_lab = (int*)(w + 278528);      // 8192 B
  float* cand_box = (float*)(w + 286720);  // 32768 B
  u64* maskArr = (u64*)(w + 319488);       // 262144 B

  heads_fused<<<256, 1024, 0, stream>>>(
      feat, obj_w_in, obj_b_in, obj_w_hid, obj_b_hid, obj_w_out, obj_b_out,
      cls_w_in, cls_b_in, cls_w_hid, cls_b_hid, cls_w_out, cls_b_out, scoreArr,
      labelArr);
  topk_kernel<<<2, 1024, 0, stream>>>(scoreArr, labelArr, cand_sc, cand_idx,
                                      cand_lab);
  box_all<<<256, 1024, 0, stream>>>(feat, cand_idx, box_w_in, box_b_in,
                                    box_w_hid, box_b_hid, box_w_out, box_b_out,
                                    cand_box);
  nms_mask<<<2000, 1024, 0, stream>>>(cand_box, maskArr);
  nms_finish<<<2, 64, 0, stream>>>(maskArr, cand_sc, cand_lab, cand_box, out);
}

// Round 5
// 926.456 us; speedup vs baseline: 1.5996x; 1.5996x over previous
//
#include <hip/hip_runtime.h>
#include <math.h>

typedef unsigned int u32;
typedef unsigned long long u64;

#define HWSZ 16384
#define NCAND 1000
#define CAP 1024
#define NDET 100

__device__ __forceinline__ float sigmoidf_(float x) {
  return 1.0f / (1.0f + expf(-x));
}

// ---------------------------------------------------------------------------
// Fused obj+cls heads — round-14.
//
// MEASURED HISTORY (do not retry):
//  r0  scalar-W (s_load_dwordx4): 580us, VALUBusy 55%, VGPR 52. Wall: scalar
//      cache serializes ~16 line misses/kb + full OOO lgkmcnt(0) drains.
//  r1/r3/r4 compiler-addressed VMEM-W: VGPR pinned at 64 (launch_bounds and
//      amdgpu_waves_per_eu both ignored) -> 12.5MB scratch spill, 1330us.
//      The 64-VGPR allocation target is IMMOVABLE for this kernel. DEAD END.
//  r2  LDS-W windows: right structure, but xv[8] batching (16 regs) pushed
//      liveness to ~70 -> 53MB scratch (202 B/thread) + staging overhead ->
//      784us @ 54.7% busy. The structure was never tested spill-free.
//
// ROUND-14 = r0 base + r2's window structure with liveness kept < 64:
//   - K in 32 windows of 8: W[:,8w..8w+8) (8KB) in a double-buffered LDS
//     tile. Staging = ONE float2 per thread per window, loaded at window
//     start (prefetch-early), ds_write at window end (write-late), one
//     barrier per window. Global-load latency hides under 512 FMA-cy.
//   - W reads: wave-uniform broadcast ds_read_b128 (in-order lgkmcnt,
//     partial waits, same-address = conflict-free).
//   - xv loaded PER KB (8 regs, not 16): acc 32 + xv 8 + nv 2 + transient
//     wv + addr ~10 = ~58 live < 64-VGPR budget. No spill expected.
// Arithmetic BIT-IDENTICAL to r0: per acc[r], k = 0..255 ascending, same
// contraction order, operands copied bitwise through LDS. absmax must be 0.
// Tripwire: WRITE_SIZE >= 10MB (spill) -> revert to r0 + tail optimization.
// ---------------------------------------------------------------------------
template <int NROWS, bool FULLROWS>
__device__ __forceinline__ void run_gemm(const float* __restrict__ Wm,
                                         const float (*X)[128],
                                         float (*Wb)[2048], int tid, int rbase,
                                         int p0, float2 acc[16]) {
#pragma unroll
  for (int r = 0; r < 16; ++r) {
    acc[r].x = 0.f;
    acc[r].y = 0.f;
  }
  const int srow = tid >> 2;       // staged row 0..255 (4 threads/row)
  const int sq = (tid & 3) * 2;    // float offset within 8-wide window
  const bool sg = srow < NROWS;    // stage guard (W has NROWS rows)
  const bool cg = rbase < NROWS;   // compute guard (this wave has rows)

  // prologue: stage window 0 into buffer 0
  if (sg) {
    float2 v = *(const float2*)(Wm + (size_t)srow * 256 + sq);
    *(float2*)&Wb[0][srow * 8 + sq] = v;
  }
  __syncthreads();

#pragma unroll 1
  for (int wn = 0; wn < 32; ++wn) {
    const int buf = wn & 1;
    // prefetch-early: issue global load for window wn+1 (used at window end)
    float2 nv;
    const bool pre = sg && (wn + 1 < 32);
    if (pre)
      nv = *(const float2*)(Wm + (size_t)srow * 256 + (wn + 1) * 8 + sq);

    if (cg) {
#pragma unroll
      for (int j = 0; j < 2; ++j) {
        const int kb = wn * 2 + j;
        const float2 xv0 = *(const float2*)&X[kb * 4 + 0][p0];
        const float2 xv1 = *(const float2*)&X[kb * 4 + 1][p0];
        const float2 xv2 = *(const float2*)&X[kb * 4 + 2][p0];
        const float2 xv3 = *(const float2*)&X[kb * 4 + 3][p0];
#pragma unroll
        for (int r = 0; r < 16; ++r) {
          if (FULLROWS || rbase + r < NROWS) {
            const float4 wv =
                *(const float4*)&Wb[buf][(rbase + r) * 8 + j * 4];
            acc[r].x += wv.x * xv0.x;
            acc[r].y += wv.x * xv0.y;
            acc[r].x += wv.y * xv1.x;
            acc[r].y += wv.y * xv1.y;
            acc[r].x += wv.z * xv2.x;
            acc[r].y += wv.z * xv2.y;
            acc[r].x += wv.w * xv3.x;
            acc[r].y += wv.w * xv3.y;
          }
        }
      }
    }
    // write-late: publish window wn+1 into the other buffer, then barrier
    if (pre) *(float2*)&Wb[buf ^ 1][srow * 8 + sq] = nv;
    __syncthreads();
  }
}

__global__ __launch_bounds__(1024) void heads_fused(
    const float* __restrict__ feat, const float* __restrict__ ow_in,
    const float* __restrict__ ob_in, const float* __restrict__ ow_hid,
    const float* __restrict__ ob_hid, const float* __restrict__ ow_out,
    const float* __restrict__ ob_out, const float* __restrict__ cw_in,
    const float* __restrict__ cb_in, const float* __restrict__ cw_hid,
    const float* __restrict__ cb_hid, const float* __restrict__ cw_out,
    const float* __restrict__ cb_out, float* __restrict__ score,
    int* __restrict__ label) {
  __shared__ __align__(16) float X[256][128];  // 128 KB
  __shared__ __align__(16) float Wb[2][2048];  // 16 KB W window double-buffer
  __shared__ float objL[128];
  __shared__ float smax[5][128];
  __shared__ int sarg[5][128];

  const int tid = threadIdx.x;
  const int wid = __builtin_amdgcn_readfirstlane(tid >> 6);
  const int ln = tid & 63;
  const int p0 = 2 * ln;
  const int rbase = wid * 16;
  const int batch = blockIdx.x >> 7;
  const int pbase = (blockIdx.x & 127) * 128;
  const float* fb = feat + (size_t)batch * 256 * HWSZ;

  for (int head = 0; head < 2; ++head) {
    const float* w_in = head ? cw_in : ow_in;
    const float* b_in = head ? cb_in : ob_in;
    const float* w_hid = head ? cw_hid : ow_hid;
    const float* b_hid = head ? cb_hid : ob_hid;

    // ---- stage feat -> X ----
#pragma unroll
    for (int m = 0; m < 8; ++m) {
      int f4 = tid + 1024 * m;
      int c = f4 >> 5, col4 = (f4 & 31) * 4;
      *(float4*)&X[c][col4] =
          *(const float4*)(fb + (size_t)c * HWSZ + pbase + col4);
    }
    __syncthreads();

    float2 acc[16];
    // ---- 5 GEMM stages (in-conv + 4 residual hidden) ----
    for (int s = 0; s < 5; ++s) {
      const float* Wm = (s == 0) ? w_in : (w_hid + (size_t)(s - 1) * 65536);
      const float* bs = (s == 0) ? b_in : (b_hid + (s - 1) * 256);
      run_gemm<256, true>(Wm, X, Wb, tid, rbase, p0, acc);
      // run_gemm ends with a barrier: all X reads complete -> safe to write.
#pragma unroll
      for (int r = 0; r < 16; ++r) {
        float b = bs[rbase + r];
        float2 v = make_float2(acc[r].x + b, acc[r].y + b);
        if (s > 0) {  // residual: h + (conv + b)
          v.x += X[rbase + r][p0];
          v.y += X[rbase + r][p0 + 1];
        }
        *(float2*)&X[rbase + r][p0] = v;
      }
      __syncthreads();  // X writes visible before next stage reads window 0
    }

    if (head == 0) {
      // ---- obj out: row 0 only ----
      run_gemm<2, false>(ow_out, X, Wb, tid, rbase, p0, acc);
      if (wid == 0) {
        float bo = ob_out[0];
        objL[p0] = sigmoidf_(acc[0].x + bo);
        objL[p0 + 1] = sigmoidf_(acc[0].y + bo);
      }
      __syncthreads();  // objL visible; X reads drained before restage
    } else {
      // ---- cls out: 80 class rows over waves 0..4 ----
      run_gemm<80, true>(cw_out, X, Wb, tid, rbase, p0, acc);
      if (rbase < 80) {
        float ob0 = objL[p0], ob1 = objL[p0 + 1];
        float best0 = -1.f, best1 = -1.f;
        int a0 = 0, a1 = 0;
#pragma unroll
        for (int r = 0; r < 16; ++r) {
          float bb = cb_out[rbase + r];
          float s0 = sigmoidf_(acc[r].x + bb) * ob0;
          float s1 = sigmoidf_(acc[r].y + bb) * ob1;
          if (s0 > best0) {
            best0 = s0;
            a0 = rbase + r;
          }
          if (s1 > best1) {
            best1 = s1;
            a1 = rbase + r;
          }
        }
        smax[wid][p0] = best0;
        sarg[wid][p0] = a0;
        smax[wid][p0 + 1] = best1;
        sarg[wid][p0 + 1] = a1;
      }
      __syncthreads();
      if (tid < 128) {
        float best = -1.f;
        int ba = 0;
        for (int g = 0; g < 5; ++g) {  // ascending class blocks: first-max wins
          float m = smax[g][tid];
          if (m > best) {
            best = m;
            ba = sarg[g][tid];
          }
        }
        score[batch * HWSZ + pbase + tid] = best;
        label[batch * HWSZ + pbase + tid] = ba;
      }
    }
  }
}

// ---------------------------------------------------------------------------
// ENTIRE box head in one kernel: 256 blocks x 8 candidates (validated r3-r9).
// ---------------------------------------------------------------------------
__global__ __launch_bounds__(1024) void box_all(
    const float* __restrict__ feat, const int* __restrict__ cand_idx,
    const float* __restrict__ w_in, const float* __restrict__ b_in,
    const float* __restrict__ w_hid, const float* __restrict__ b_hid,
    const float* __restrict__ w_out, const float* __restrict__ b_out,
    float* __restrict__ cand_box) {
  __shared__ float h[256][8];  // 8 KB
  const int tid = threadIdx.x;
  const int batch = blockIdx.x >> 7;
  const int cbase = (blockIdx.x & 127) * 8;
  const float* fb = feat + (size_t)batch * 256 * HWSZ;

  for (int i = tid; i < 2048; i += 1024) {
    int k = i >> 3, c = i & 7;
    int r = cbase + c;
    float v = 0.f;
    if (r < NCAND) {
      int hw = cand_idx[batch * CAP + r];
      v = fb[(size_t)k * HWSZ + hw];
    }
    h[k][c] = v;
  }
  __syncthreads();

  const int wid = tid >> 6, ln = tid & 63;
  const int c = ln & 7, rr = ln >> 3;
  const int r0 = wid * 16 + rr, r1 = wid * 16 + 8 + rr;

  for (int s = 0; s < 5; ++s) {
    const float* Wm = (s == 0) ? w_in : (w_hid + (size_t)(s - 1) * 65536);
    const float* bs = (s == 0) ? b_in : (b_hid + (s - 1) * 256);
    float a0 = 0.f, a1 = 0.f;
    for (int kb = 0; kb < 64; ++kb) {
      float4 w0 = *(const float4*)&Wm[(size_t)r0 * 256 + kb * 4];
      float4 w1 = *(const float4*)&Wm[(size_t)r1 * 256 + kb * 4];
      float x0 = h[kb * 4 + 0][c], x1 = h[kb * 4 + 1][c];
      float x2 = h[kb * 4 + 2][c], x3 = h[kb * 4 + 3][c];
      a0 += w0.x * x0;
      a0 += w0.y * x1;
      a0 += w0.z * x2;
      a0 += w0.w * x3;
      a1 += w1.x * x0;
      a1 += w1.y * x1;
      a1 += w1.z * x2;
      a1 += w1.w * x3;
    }
    __syncthreads();
    float v0 = a0 + bs[r0], v1 = a1 + bs[r1];
    if (s > 0) {
      v0 += h[r0][c];
      v1 += h[r1][c];
    }
    h[r0][c] = v0;
    h[r1][c] = v1;
    __syncthreads();
  }

  if (tid < 32) {
    int row = tid >> 3, cc = tid & 7;
    int r = cbase + cc;
    if (r < NCAND) {
      float s = 0.f;
      for (int k = 0; k < 256; ++k) s += w_out[row * 256 + k] * h[k][cc];
      s += b_out[row];
      float e = expf(s) * 8.f;
      int hw = cand_idx[batch * CAP + r];
      int hh = hw >> 7, wwp = hw & 127;
      float px = (wwp + 0.5f) * 8.f, py = (hh + 0.5f) * 8.f;
      float coord = (row == 0)   ? px - e
                    : (row == 1) ? py - e
                    : (row == 2) ? px + e
                                 : py + e;
      cand_box[(size_t)(batch * CAP + r) * 4 + row] = coord;
    }
  }
}

// ---------------------------------------------------------------------------
// Exact top-1000 per batch (bitwise-validated rounds 1-9). Skip the
// 2048-wide tie bitonic when only one element equals the threshold (the
// overwhelmingly common case for continuous scores); general path kept.
// ---------------------------------------------------------------------------
__device__ __forceinline__ void suffix2048(u32* hist, int tid) {
  for (int d = 1; d < 2048; d <<= 1) {
    u32 v0 = hist[tid] + ((tid + d < 2048) ? hist[tid + d] : 0u);
    u32 v1 =
        hist[tid + 1024] + ((tid + 1024 + d < 2048) ? hist[tid + 1024 + d] : 0u);
    __syncthreads();
    hist[tid] = v0;
    hist[tid + 1024] = v1;
    __syncthreads();
  }
}

__global__ __launch_bounds__(1024) void topk_kernel(
    const float* __restrict__ score, const int* __restrict__ label,
    float* __restrict__ cand_sc, int* __restrict__ cand_idx,
    int* __restrict__ cand_lab) {
  __shared__ u32 hist[2048];
  __shared__ u64 buf[CAP];
  __shared__ u32 tiebuf[2048];
  __shared__ int sres[2];
  __shared__ int cA, cT;
  const int tid = threadIdx.x;
  const int b = blockIdx.x;
  const int base = b * HWSZ;
  u32 bits[16];
#pragma unroll
  for (int m = 0; m < 16; ++m)
    bits[m] = __float_as_uint(score[base + tid + 1024 * m]);

  int K = NCAND;
  u32 hi = 0;
  u32 thresh = 0;
  for (int lev = 0; lev < 3; ++lev) {
    hist[tid] = 0;
    hist[tid + 1024] = 0;
    __syncthreads();
#pragma unroll
    for (int m = 0; m < 16; ++m) {
      u32 v = bits[m];
      bool ok;
      int bin;
      if (lev == 0) {
        ok = true;
        bin = v >> 21;
      } else if (lev == 1) {
        ok = ((v >> 21) == hi);
        bin = (v >> 10) & 2047;
      } else {
        ok = ((v >> 10) == hi);
        bin = v & 1023;
      }
      if (ok) atomicAdd(&hist[bin], 1u);
    }
    __syncthreads();
    suffix2048(hist, tid);
#pragma unroll
    for (int e = 0; e < 2; ++e) {
      int i = tid + e * 1024;
      int Si = (int)hist[i];
      int Sn = (i + 1 < 2048) ? (int)hist[i + 1] : 0;
      if (Si >= K && Sn < K) {
        sres[0] = i;
        sres[1] = Sn;
      }
    }
    __syncthreads();
    int B = sres[0];
    K -= sres[1];
    if (lev == 0) hi = (u32)B;
    else if (lev == 1) hi = (hi << 11) | (u32)B;
    else thresh = (hi << 10) | (u32)B;
    __syncthreads();
  }
  const int T = K;

  if (tid == 0) {
    cA = 0;
    cT = 0;
  }
  __syncthreads();
#pragma unroll
  for (int m = 0; m < 16; ++m) {
    u32 v = bits[m];
    int idxp = tid + 1024 * m;
    if (v > thresh) {
      int pos = atomicAdd(&cA, 1);
      buf[pos] = ((u64)(~v) << 32) | (u32)idxp;
    } else if (v == thresh) {
      int pos = atomicAdd(&cT, 1);
      if (pos < 2048) tiebuf[pos] = (u32)idxp;
    }
  }
  __syncthreads();
  const int A = cA;
  int nT = cT < 2048 ? cT : 2048;
  for (int i = tid; i < 2048; i += 1024)
    if (i >= nT) tiebuf[i] = 0xFFFFFFFFu;
  __syncthreads();
  if (nT > 1) {  // sort ties ascending by pixel index (rare path)
    for (int k = 2; k <= 2048; k <<= 1)
      for (int j = k >> 1; j > 0; j >>= 1) {
#pragma unroll
        for (int e = 0; e < 2; ++e) {
          int i = tid + e * 1024;
          int l = i ^ j;
          if (l > i) {
            u32 a = tiebuf[i], bb = tiebuf[l];
            bool up = ((i & k) == 0);
            if ((a > bb) == up) {
              tiebuf[i] = bb;
              tiebuf[l] = a;
            }
          }
        }
        __syncthreads();
      }
  }
  for (int t2 = tid; t2 < T; t2 += 1024)
    buf[A + t2] = ((u64)(~thresh) << 32) | tiebuf[t2];
  for (int i = tid; i < CAP; i += 1024)
    if (i >= NCAND) buf[i] = 0xFFFFFFFFFFFFFFFFull;
  __syncthreads();
  for (int k = 2; k <= 1024; k <<= 1)
    for (int j = k >> 1; j > 0; j >>= 1) {
      int i = tid, l = i ^ j;
      if (l > i) {
        u64 a = buf[i], bb = buf[l];
        bool up = ((i & k) == 0);
        if ((a > bb) == up) {
          buf[i] = bb;
          buf[l] = a;
        }
      }
      __syncthreads();
    }
  if (tid < NCAND) {
    u64 kv = buf[tid];
    u32 sb = ~(u32)(kv >> 32);
    int pix = (int)(kv & 0xFFFFFFFFull);
    cand_sc[b * CAP + tid] = __uint_as_float(sb);
    cand_idx[b * CAP + tid] = pix;
    cand_lab[b * CAP + tid] = label[base + pix];
  }
}

// ---------------------------------------------------------------------------
// NMS mask + fused sequential-suppress/assemble (unchanged, validated).
// ---------------------------------------------------------------------------
__global__ __launch_bounds__(1024) void nms_mask(
    const float* __restrict__ cand_box, u64* __restrict__ mask) {
  int bid = blockIdx.x;
  int b = bid / NCAND, i = bid % NCAND;
  int j = threadIdx.x;
  const float* bi = cand_box + (size_t)(b * CAP + i) * 4;
  float ix1 = bi[0], iy1 = bi[1], ix2 = bi[2], iy2 = bi[3];
  bool pred = false;
  if (j < NCAND && j > i) {
    const float* bj = cand_box + (size_t)(b * CAP + j) * 4;
    float jx1 = bj[0], jy1 = bj[1], jx2 = bj[2], jy2 = bj[3];
    float ai = fmaxf(ix2 - ix1, 0.f) * fmaxf(iy2 - iy1, 0.f);
    float aj = fmaxf(jx2 - jx1, 0.f) * fmaxf(jy2 - jy1, 0.f);
    float lx = fmaxf(ix1, jx1), ly = fmaxf(iy1, jy1);
    float rx = fminf(ix2, jx2), ry = fminf(iy2, jy2);
    float w = fmaxf(rx - lx, 0.f), h = fmaxf(ry - ly, 0.f);
    float inter = w * h;
    float iou = inter / (ai + aj - inter + 1e-6f);
    pred = iou > 0.65f;
  }
  u64 word = __ballot(pred);
  if ((j & 63) == 0) mask[(size_t)b * 16384 + i * 16 + (j >> 6)] = word;
}

__global__ void nms_finish(const u64* __restrict__ mask,
                           const float* __restrict__ cand_sc,
                           const int* __restrict__ cand_lab,
                           const float* __restrict__ cand_box,
                           float* __restrict__ out) {
  __shared__ u64 M[16000];
  int b = blockIdx.x, lane = threadIdx.x;  // 64 threads
  for (int m = lane; m < 16000; m += 64) M[m] = mask[(size_t)b * 16384 + m];
  __syncthreads();
  u64 kw = 0ull;
  if (lane < 15) kw = ~0ull;
  else if (lane == 15) kw = (1ull << 40) - 1;
  for (int i = 0; i < NCAND; ++i) {
    u64 wi = __shfl(kw, i >> 6);
    if ((wi >> (i & 63)) & 1ull) {
      if (lane < 16) kw &= ~M[i * 16 + lane];
    }
  }
  u64 valid = 0ull;
  if (lane < 15) valid = ~0ull;
  else if (lane == 15) valid = (1ull << 40) - 1;
  kw &= valid;
  u64 sup = valid & ~kw;
  int ck = __popcll(kw), cs = __popcll(sup);
  int preK = 0, preS = 0, totK = 0;
  for (int q = 0; q < 16; ++q) {
    int vk = __shfl(ck, q), vs = __shfl(cs, q);
    if (q < lane) {
      preK += vk;
      preS += vs;
    }
    totK += vk;
  }
  float* obox = out;
  float* osc = out + 2 * NDET * 4;
  float* olab = out + 2 * NDET * 4 + 2 * NDET;
  if (lane < 16) {
    u64 m = kw;
    int pos = preK;
    while (m) {
      int bit = __ffsll((unsigned long long)m) - 1;
      m &= m - 1;
      int j = lane * 64 + bit;
      if (pos < NDET) {
        osc[b * NDET + pos] = cand_sc[b * CAP + j];
        olab[b * NDET + pos] = (float)cand_lab[b * CAP + j];
        const float* bx = cand_box + (size_t)(b * CAP + j) * 4;
        float* dst = obox + (size_t)(b * NDET + pos) * 4;
        dst[0] = bx[0];
        dst[1] = bx[1];
        dst[2] = bx[2];
        dst[3] = bx[3];
      }
      ++pos;
    }
    m = sup;
    pos = totK + preS;
    while (m) {
      int bit = __ffsll((unsigned long long)m) - 1;
      m &= m - 1;
      int j = lane * 64 + bit;
      if (pos < NDET) {
        osc[b * NDET + pos] = 0.0f;
        olab[b * NDET + pos] = (float)cand_lab[b * CAP + j];
        const float* bx = cand_box + (size_t)(b * CAP + j) * 4;
        float* dst = obox + (size_t)(b * NDET + pos) * 4;
        dst[0] = bx[0];
        dst[1] = bx[1];
        dst[2] = bx[2];
        dst[3] = bx[3];
      }
      ++pos;
    }
  }
}

extern "C" void kernel_launch(void* const* d_in, const int* in_sizes, int n_in,
                              void* d_out, int out_size, void* d_ws,
                              size_t ws_size, hipStream_t stream) {
  (void)in_sizes;
  (void)n_in;
  (void)out_size;
  (void)ws_size;
  const float* feat = (const float*)d_in[0];
  const float* cls_w_in = (const float*)d_in[1];
  const float* cls_b_in = (const float*)d_in[2];
  const float* cls_w_hid = (const float*)d_in[3];
  const float* cls_b_hid = (const float*)d_in[4];
  const float* cls_w_out = (const float*)d_in[5];
  const float* cls_b_out = (const float*)d_in[6];
  const float* obj_w_in = (const float*)d_in[7];
  const float* obj_b_in = (const float*)d_in[8];
  const float* obj_w_hid = (const float*)d_in[9];
  const float* obj_b_hid = (const float*)d_in[10];
  const float* obj_w_out = (const float*)d_in[11];
  const float* obj_b_out = (const float*)d_in[12];
  const float* box_w_in = (const float*)d_in[13];
  const float* box_b_in = (const float*)d_in[14];
  const float* box_w_hid = (const float*)d_in[15];
  const float* box_b_hid = (const float*)d_in[16];
  const float* box_w_out = (const float*)d_in[17];
  const float* box_b_out = (const float*)d_in[18];
  float* out = (float*)d_out;

  char* w = (char*)d_ws;
  float* scoreArr = (float*)w;             // 131072 B
  int* labelArr = (int*)(w + 131072);      // 131072 B
  float* cand_sc = (float*)(w + 262144);   // 8192 B
  int* cand_idx = (int*)(w + 270336);      // 8192 B
  int* cand_lab = (int*)(w + 278528);      // 8192 B
  float* cand_box = (float*)(w + 286720);  // 32768 B
  u64* maskArr = (u64*)(w + 319488);       // 262144 B

  heads_fused<<<256, 1024, 0, stream>>>(
      feat, obj_w_in, obj_b_in, obj_w_hid, obj_b_hid, obj_w_out, obj_b_out,
      cls_w_in, cls_b_in, cls_w_hid, cls_b_hid, cls_w_out, cls_b_out, scoreArr,
      labelArr);
  topk_kernel<<<2, 1024, 0, stream>>>(scoreArr, labelArr, cand_sc, cand_idx,
                                      cand_lab);
  box_all<<<256, 1024, 0, stream>>>(feat, cand_idx, box_w_in, box_b_in,
                                    box_w_hid, box_b_hid, box_w_out, box_b_out,
                                    cand_box);
  nms_mask<<<2000, 1024, 0, stream>>>(cand_box, maskArr);
  nms_finish<<<2, 64, 0, stream>>>(maskArr, cand_sc, cand_lab, cand_box, out);
}